// Round 1
// baseline (382.564 us; speedup 1.0000x reference)
//
#include <hip/hip_runtime.h>
#include <hip/hip_bf16.h>

// Problem constants (from reference):
//   xyz:     (N=8, 3, H=64, W=2048) f32
//   softmax: (N=8, C=20, H, W) f32
//   mask:    (N=8, H, W) bool -> int32 on upload
//   out:     (N, C, H, W) f32
// out[n,c,h,w] = sum_{di,dj in 5x5 window, in-bounds}
//                  exp(-0.5 * ||xyz[n,:,hi,wi] - xyz[n,:,h,w]||^2)
//                  * mask[n,hi,wi] * softmax[n,c,hi,wi]
// (xyz wrap-pad is irrelevant: zero-padded softmax kills all OOB taps.)

#define H_DIM 64
#define W_DIM 2048
#define C_DIM 20
#define N_DIM 8
#define HW (H_DIM * W_DIM)

__global__ __launch_bounds__(256) void lcx_kernel(
    const float* __restrict__ xyz,
    const float* __restrict__ sm,
    const int*  __restrict__ mask,
    float* __restrict__ out)
{
    const int idx = blockIdx.x * blockDim.x + threadIdx.x;  // pixel id, 0..N*H*W-1
    const int w  = idx & (W_DIM - 1);
    const int hn = idx >> 11;            // / W_DIM
    const int h  = hn & (H_DIM - 1);
    const int n  = hn >> 6;              // / H_DIM

    const float* xyzn  = xyz  + (size_t)n * 3 * HW;
    const int*   maskn = mask + (size_t)n * HW;
    const int    ctr   = h * W_DIM + w;

    const float cx = xyzn[0 * HW + ctr];
    const float cy = xyzn[1 * HW + ctr];
    const float cz = xyzn[2 * HW + ctr];

    float wgt[25];
    int   off[25];

    #pragma unroll
    for (int di = 0; di < 5; ++di) {
        const int hi  = h + di - 2;
        const bool hok = ((unsigned)hi < (unsigned)H_DIM);
        #pragma unroll
        for (int dj = 0; dj < 5; ++dj) {
            const int wi = w + dj - 2;
            const bool ok = hok && ((unsigned)wi < (unsigned)W_DIM);
            const int k  = di * 5 + dj;
            const int o  = hi * W_DIM + wi;
            off[k] = ok ? o : 0;           // safe dummy offset when OOB
            float wv = 0.0f;
            if (ok) {
                const float dx = xyzn[0 * HW + o] - cx;
                const float dy = xyzn[1 * HW + o] - cy;
                const float dz = xyzn[2 * HW + o] - cz;
                const float d2 = dx * dx + dy * dy + dz * dz;
                wv = __expf(-0.5f * d2);
                wv = maskn[o] ? wv : 0.0f;
            }
            wgt[k] = wv;
        }
    }

    const float* smn  = sm  + (size_t)n * C_DIM * HW;
    float*       outn = out + (size_t)n * C_DIM * HW;

    #pragma unroll 4
    for (int c = 0; c < C_DIM; ++c) {
        const float* smc = smn + (size_t)c * HW;
        float acc = 0.0f;
        #pragma unroll
        for (int k = 0; k < 25; ++k) {
            acc = fmaf(wgt[k], smc[off[k]], acc);
        }
        outn[(size_t)c * HW + ctr] = acc;
    }
}

extern "C" void kernel_launch(void* const* d_in, const int* in_sizes, int n_in,
                              void* d_out, int out_size, void* d_ws, size_t ws_size,
                              hipStream_t stream)
{
    const float* xyz  = (const float*)d_in[0];
    const float* sm   = (const float*)d_in[1];
    const int*   mask = (const int*)d_in[2];
    float*       out  = (float*)d_out;

    const int n_pix  = N_DIM * H_DIM * W_DIM;      // 1,048,576
    const int block  = 256;
    const int grid   = n_pix / block;              // 4096

    lcx_kernel<<<grid, block, 0, stream>>>(xyz, sm, mask, out);
}

// Round 2
// 251.471 us; speedup vs baseline: 1.5213x; 1.5213x over previous
//
#include <hip/hip_runtime.h>
#include <hip/hip_bf16.h>

// out[n,c,h,w] = sum_{5x5 in-bounds taps} exp(-0.5*||xyz_nbr - xyz_ctr||^2)
//                * mask_nbr * softmax[n,c,nbr]
// Zero-padded softmax => OOB taps contribute 0; clamped loads under zero
// weights are safe (finite garbage * 0.0f).
// Each thread computes 4 consecutive w outputs for all 20 channels:
// per (row, channel) the window is 8 contiguous floats -> float2+float4+float2.

#define H_DIM 64
#define W_DIM 2048
#define C_DIM 20
#define N_DIM 8
#define HW (H_DIM * W_DIM)

__global__ __launch_bounds__(256) void lcx_kernel(
    const float* __restrict__ xyz,
    const float* __restrict__ sm,
    const int*  __restrict__ mask,
    float* __restrict__ out)
{
    const int tid = blockIdx.x * blockDim.x + threadIdx.x;   // 0..262143
    const int w  = (tid & (W_DIM / 4 - 1)) << 2;             // 0,4,...,2044
    const int hn = tid >> 9;                                 // /(W/4)
    const int h  = hn & (H_DIM - 1);
    const int n  = hn >> 6;

    const float* xyzn  = xyz  + (size_t)n * 3 * HW;
    const int*   maskn = mask + (size_t)n * HW;
    const float* smn   = sm   + (size_t)n * C_DIM * HW;
    float*       outn  = out  + (size_t)n * C_DIM * HW;

    const int ctr = h * W_DIM + w;

    // center coords for the 4 pixels (vector load)
    const float4 cxv = *(const float4*)(xyzn + 0 * HW + ctr);
    const float4 cyv = *(const float4*)(xyzn + 1 * HW + ctr);
    const float4 czv = *(const float4*)(xyzn + 2 * HW + ctr);
    const float cx[4] = {cxv.x, cxv.y, cxv.z, cxv.w};
    const float cy[4] = {cyv.x, cyv.y, cyv.z, cyv.w};
    const float cz[4] = {czv.x, czv.y, czv.z, czv.w};

    float4 acc[C_DIM];
    #pragma unroll
    for (int c = 0; c < C_DIM; ++c) acc[c] = make_float4(0.f, 0.f, 0.f, 0.f);

    // clamped column bases; columns covered: [w-2 .. w+5]
    const int b0 = (w >= 2) ? (w - 2) : 0;                        // float2 (8B-aligned)
    const int b1 = w;                                             // float4 (16B-aligned)
    const int b2 = (w + 4 <= W_DIM - 2) ? (w + 4) : (W_DIM - 2);  // float2

    #pragma unroll
    for (int di = 0; di < 5; ++di) {
        const int hi = h + di - 2;
        if ((unsigned)hi >= (unsigned)H_DIM) continue;   // block-uniform skip
        const int rb = hi * W_DIM;

        // xyz row segments: 8 columns [w-2 .. w+5] per plane
        float xs[8], ys[8], zs[8];
        {
            const float* px = xyzn + 0 * HW + rb;
            const float2 t0 = *(const float2*)(px + b0);
            const float4 t1 = *(const float4*)(px + b1);
            const float2 t2 = *(const float2*)(px + b2);
            xs[0]=t0.x; xs[1]=t0.y; xs[2]=t1.x; xs[3]=t1.y;
            xs[4]=t1.z; xs[5]=t1.w; xs[6]=t2.x; xs[7]=t2.y;
        }
        {
            const float* py = xyzn + 1 * HW + rb;
            const float2 t0 = *(const float2*)(py + b0);
            const float4 t1 = *(const float4*)(py + b1);
            const float2 t2 = *(const float2*)(py + b2);
            ys[0]=t0.x; ys[1]=t0.y; ys[2]=t1.x; ys[3]=t1.y;
            ys[4]=t1.z; ys[5]=t1.w; ys[6]=t2.x; ys[7]=t2.y;
        }
        {
            const float* pz = xyzn + 2 * HW + rb;
            const float2 t0 = *(const float2*)(pz + b0);
            const float4 t1 = *(const float4*)(pz + b1);
            const float2 t2 = *(const float2*)(pz + b2);
            zs[0]=t0.x; zs[1]=t0.y; zs[2]=t1.x; zs[3]=t1.y;
            zs[4]=t1.z; zs[5]=t1.w; zs[6]=t2.x; zs[7]=t2.y;
        }
        int ms[8];
        {
            const int* pm = maskn + rb;
            const int2 m0 = *(const int2*)(pm + b0);
            const int4 m1 = *(const int4*)(pm + b1);
            const int2 m2 = *(const int2*)(pm + b2);
            ms[0]=m0.x; ms[1]=m0.y; ms[2]=m1.x; ms[3]=m1.y;
            ms[4]=m1.z; ms[5]=m1.w; ms[6]=m2.x; ms[7]=m2.y;
        }

        // 20 weights for this row (4 pixels x 5 dj taps)
        float wgt[4][5];
        #pragma unroll
        for (int p = 0; p < 4; ++p) {
            #pragma unroll
            for (int dj = 0; dj < 5; ++dj) {
                const int s = p + dj;                     // seg index, col = w-2+s
                const float dx = xs[s] - cx[p];
                const float dy = ys[s] - cy[p];
                const float dz = zs[s] - cz[p];
                const float d2 = fmaf(dx, dx, fmaf(dy, dy, dz * dz));
                const bool ok = ((unsigned)(w - 2 + s) < (unsigned)W_DIM) && (ms[s] != 0);
                wgt[p][dj] = ok ? __expf(-0.5f * d2) : 0.0f;
            }
        }

        // 20 channels: 3 wide loads + 20 FMAs each
        #pragma unroll
        for (int c = 0; c < C_DIM; ++c) {
            const float* pr = smn + (size_t)c * HW + rb;
            const float2 f0 = *(const float2*)(pr + b0);
            const float4 f1 = *(const float4*)(pr + b1);
            const float2 f2 = *(const float2*)(pr + b2);
            float fs[8];
            fs[0]=f0.x; fs[1]=f0.y; fs[2]=f1.x; fs[3]=f1.y;
            fs[4]=f1.z; fs[5]=f1.w; fs[6]=f2.x; fs[7]=f2.y;

            #pragma unroll
            for (int p = 0; p < 4; ++p) {
                float a = (p == 0) ? acc[c].x : (p == 1) ? acc[c].y
                        : (p == 2) ? acc[c].z : acc[c].w;
                #pragma unroll
                for (int dj = 0; dj < 5; ++dj)
                    a = fmaf(wgt[p][dj], fs[p + dj], a);
                if      (p == 0) acc[c].x = a;
                else if (p == 1) acc[c].y = a;
                else if (p == 2) acc[c].z = a;
                else             acc[c].w = a;
            }
        }
    }

    #pragma unroll
    for (int c = 0; c < C_DIM; ++c)
        *(float4*)(outn + (size_t)c * HW + ctr) = acc[c];
}

extern "C" void kernel_launch(void* const* d_in, const int* in_sizes, int n_in,
                              void* d_out, int out_size, void* d_ws, size_t ws_size,
                              hipStream_t stream)
{
    const float* xyz  = (const float*)d_in[0];
    const float* sm   = (const float*)d_in[1];
    const int*   mask = (const int*)d_in[2];
    float*       out  = (float*)d_out;

    const int n_thr = N_DIM * H_DIM * (W_DIM / 4);   // 262,144
    const int block = 256;
    const int grid  = n_thr / block;                 // 1024

    lcx_kernel<<<grid, block, 0, stream>>>(xyz, sm, mask, out);
}